// Round 3
// baseline (644.215 us; speedup 1.0000x reference)
//
#include <hip/hip_runtime.h>
#include <hip/hip_bf16.h>
#include <stdint.h>

// Problem constants
#define HEADS 16
#define DH    64
#define NB    8
#define MQ    256     // latents per batch
#define MX    4096    // media tokens per batch
#define JD    4352    // MX + MQ
#define DIMV  1024

typedef __bf16 bf16;
typedef __bf16 bf16x8 __attribute__((ext_vector_type(8)));
typedef float  f32x4  __attribute__((ext_vector_type(4)));

// XOR swizzle of 16B chunks within a 64-col (8-chunk) LDS row.
#define SWZ(r, c) (((c) ^ ((r) & 7)))

__device__ __forceinline__ void gl_lds16(const void* g, void* l) {
  __builtin_amdgcn_global_load_lds((const __attribute__((address_space(1))) void*)g,
                                   (__attribute__((address_space(3))) void*)l, 16, 0, 0);
}

// ---------------- LayerNorm: one WAVE per row (no barriers, no LDS) ---------
__global__ __launch_bounds__(256) void ln_kernel(
    const float* __restrict__ X, const float* __restrict__ gw, const float* __restrict__ bw,
    bf16* __restrict__ out_kv, bf16* __restrict__ out_ln, int is_lat)
{
  const int row  = blockIdx.x * 4 + (threadIdx.x >> 6);
  const int lane = threadIdx.x & 63;
  const float* src = X + (size_t)row * DIMV + lane * 4;
  float4 v[4];
#pragma unroll
  for (int p = 0; p < 4; p++) v[p] = *(const float4*)(src + p * 256);
  float s = 0.f, s2 = 0.f;
#pragma unroll
  for (int p = 0; p < 4; p++) {
    s  += v[p].x + v[p].y + v[p].z + v[p].w;
    s2 += v[p].x*v[p].x + v[p].y*v[p].y + v[p].z*v[p].z + v[p].w*v[p].w;
  }
#pragma unroll
  for (int m = 1; m < 64; m <<= 1) { s += __shfl_xor(s, m); s2 += __shfl_xor(s2, m); }
  const float mu  = s * (1.0f / DIMV);
  const float var = s2 * (1.0f / DIMV) - mu * mu;
  const float rst = rsqrtf(var + 1e-5f);
  size_t kvrow;
  if (is_lat) { int b = row >> 8;  int i = row & 255;  kvrow = (size_t)b * JD + MX + i; }
  else        { int b = row >> 12; int j = row & 4095; kvrow = (size_t)b * JD + j; }
  bf16* dst = out_kv + kvrow * DIMV + lane * 4;
#pragma unroll
  for (int p = 0; p < 4; p++) {
    const float4 g4 = *(const float4*)(gw + p * 256 + lane * 4);
    const float4 b4 = *(const float4*)(bw + p * 256 + lane * 4);
    union { bf16 h[4]; short4 s4; } u;
    u.h[0] = (bf16)((v[p].x - mu) * rst * g4.x + b4.x);
    u.h[1] = (bf16)((v[p].y - mu) * rst * g4.y + b4.y);
    u.h[2] = (bf16)((v[p].z - mu) * rst * g4.z + b4.z);
    u.h[3] = (bf16)((v[p].w - mu) * rst * g4.w + b4.w);
    *(short4*)(dst + p * 256) = u.s4;
    if (is_lat) *(short4*)(out_ln + (size_t)row * DIMV + p * 256 + lane * 4) = u.s4;
  }
}

// ---------------- Weight transpose + f32->bf16: in[R][C] -> out[C][R] --------
__global__ __launch_bounds__(256) void transpose_w(
    const float* __restrict__ in, bf16* __restrict__ out, int R, int C)
{
  __shared__ float t[64][65];
  const int tilesC = C >> 6;
  const int tc = blockIdx.x % tilesC, tr = blockIdx.x / tilesC;
  const int r0 = tr << 6, c0 = tc << 6;
  const int lr = threadIdx.x >> 4;
  const int lc = (threadIdx.x & 15) << 2;
#pragma unroll
  for (int p = 0; p < 4; p++) {
    float4 v = *(const float4*)&in[(size_t)(r0 + lr + p*16) * C + c0 + lc];
    t[lr + p*16][lc    ] = v.x; t[lr + p*16][lc + 1] = v.y;
    t[lr + p*16][lc + 2] = v.z; t[lr + p*16][lc + 3] = v.w;
  }
  __syncthreads();
#pragma unroll
  for (int p = 0; p < 4; p++) {
    const int oc = lr + p*16;
    union { bf16 h[4]; short4 s4; } u;
    u.h[0] = (bf16)t[lc    ][oc]; u.h[1] = (bf16)t[lc + 1][oc];
    u.h[2] = (bf16)t[lc + 2][oc]; u.h[3] = (bf16)t[lc + 3][oc];
    *(short4*)&out[(size_t)(c0 + oc) * R + r0 + lc] = u.s4;
  }
}

// ---------------- mask dtype detect (vectorized) + build --------------------
__global__ __launch_bounds__(256) void mask_detect(
    const uint4* __restrict__ m, int n16, int* __restrict__ flag)
{
  const int tid = threadIdx.x;
  int cnt = 0;
  for (int i = tid; i < n16; i += 256) {
    uint4 v = m[i];
    const unsigned w[4] = {v.x, v.y, v.z, v.w};
#pragma unroll
    for (int k = 0; k < 4; k++) {
      cnt += ((w[k]       ) & 255u) != 0;
      cnt += ((w[k] >>  8 ) & 255u) != 0;
      cnt += ((w[k] >> 16 ) & 255u) != 0;
      cnt += ((w[k] >> 24 ) & 255u) != 0;
    }
  }
#pragma unroll
  for (int mm = 1; mm < 64; mm <<= 1) cnt += __shfl_xor(cnt, mm);
  __shared__ int r4[4];
  if ((tid & 63) == 0) r4[tid >> 6] = cnt;
  __syncthreads();
  if (tid == 0) {
    int t = r4[0] + r4[1] + r4[2] + r4[3];
    flag[0] = (t * 16 > n16 * 16 * 5) ? 1 : 0;   // frac > 0.3125 -> byte mode
  }
}

__global__ __launch_bounds__(256) void mask_build(
    const void* __restrict__ mraw, const int* __restrict__ flag, float* __restrict__ mm)
{
  const int idx = blockIdx.x * 256 + threadIdx.x;   // < 34816
  const int b = idx / JD, j = idx - b * JD;
  float v = 1.0f;
  if (j < MX) {
    bool masked = (*flag) ? (((const unsigned char*)mraw)[b * MX + j] != 0)
                          : (((const int*)mraw)[b * MX + j] != 0);
    v = masked ? 0.0f : 1.0f;
  }
  mm[idx] = v;
}

// ---------------- GEMM: 128x128 tile, BK=64, swizzled LDS -------------------
// mode 0: Cf[row][n0+col] f32 direct.
// mode 1: bx < kSplitX : rows-mode -> outR row-major bf16;
//         bx >= kSplitX: V-mode (operands swapped) -> outVT[bh][d][j] coalesced.
// y_off: m-tile offset (kv GEMM split into 4 dispatches for profiling).
__global__ __launch_bounds__(256) void gemm128(
    const bf16* __restrict__ A, const bf16* __restrict__ Bt,
    float* __restrict__ Cf, bf16* __restrict__ outR, bf16* __restrict__ outVT,
    int N, int K, int kSplitX, int mode, int y_off)
{
  __shared__ bf16 smem[2 * 128 * 64];
  bf16* As = smem;
  bf16* Bs = smem + 128 * 64;
  bf16* Ct = smem;                       // epilogue alias

  const int tid = threadIdx.x;
  const int lane = tid & 63, wid = tid >> 6;
  const int wr = wid >> 1, wc = wid & 1;
  const int bx = blockIdx.x;
  const int m0 = (y_off + blockIdx.y) * 128;
  const bool vmode = (mode == 1) && (bx >= kSplitX);
  const int n0 = vmode ? 1024 + (bx - kSplitX) * 128 : bx * 128;
  const int srow = tid >> 3, sc = tid & 7;
  const int ssw = SWZ(srow, sc) * 8;
  const int lc = lane & 15, lq = lane >> 4;

  f32x4 acc[4][4];
#pragma unroll
  for (int i = 0; i < 4; i++)
#pragma unroll
    for (int j = 0; j < 4; j++)
#pragma unroll
      for (int r = 0; r < 4; r++) acc[i][j][r] = 0.f;

  const bf16* Arow = vmode ? (Bt + (size_t)n0 * K) : (A + (size_t)m0 * K);
  const bf16* Brow = vmode ? (A + (size_t)m0 * K) : (Bt + (size_t)n0 * K);
  const bf16* Abase = Arow + (size_t)srow * K + ssw;
  const bf16* Bbase = Brow + (size_t)srow * K + ssw;

  for (int k0 = 0; k0 < K; k0 += 64) {
    __syncthreads();
#pragma unroll
    for (int q = 0; q < 4; q++) {
      gl_lds16(Abase + (size_t)q * 32 * K + k0, &As[(srow + q*32) * 64 + sc*8]);
      gl_lds16(Bbase + (size_t)q * 32 * K + k0, &Bs[(srow + q*32) * 64 + sc*8]);
    }
    asm volatile("s_waitcnt vmcnt(0)" ::: "memory");
    __syncthreads();
#pragma unroll
    for (int kk = 0; kk < 2; kk++) {
      bf16x8 af[4], bfr[4];
#pragma unroll
      for (int mi = 0; mi < 4; mi++)
        af[mi] = *(const bf16x8*)&As[(wr*64 + mi*16 + lc) * 64 + SWZ(lc, kk*4 + lq)*8];
#pragma unroll
      for (int ni = 0; ni < 4; ni++)
        bfr[ni] = *(const bf16x8*)&Bs[(wc*64 + ni*16 + lc) * 64 + SWZ(lc, kk*4 + lq)*8];
#pragma unroll
      for (int mi = 0; mi < 4; mi++)
#pragma unroll
        for (int ni = 0; ni < 4; ni++)
          acc[mi][ni] = __builtin_amdgcn_mfma_f32_16x16x32_bf16(af[mi], bfr[ni], acc[mi][ni], 0, 0, 0);
    }
  }

  if (mode == 0) {
#pragma unroll
    for (int mi = 0; mi < 4; mi++)
#pragma unroll
      for (int ni = 0; ni < 4; ni++) {
        const int r = m0 + wr*64 + mi*16 + lq*4;
        const int c = n0 + wc*64 + ni*16 + lc;
#pragma unroll
        for (int reg = 0; reg < 4; reg++)
          Cf[(size_t)(r + reg) * N + c] = acc[mi][ni][reg];
      }
    return;
  }

  __syncthreads();
#pragma unroll
  for (int mi = 0; mi < 4; mi++)
#pragma unroll
    for (int ni = 0; ni < 4; ni++) {
      const int col = wc*64 + ni*16 + lc;
      const int cch = col >> 3, cw = col & 7;
#pragma unroll
      for (int reg = 0; reg < 4; reg++) {
        const int row = wr*64 + mi*16 + lq*4 + reg;
        Ct[row*128 + ((cch ^ (row & 15)) << 3) + cw] = (bf16)acc[mi][ni][reg];
      }
    }
  __syncthreads();

  const int cch = tid & 15, r0 = tid >> 4;
  if (!vmode) {
    bf16* dst0 = outR + (size_t)m0 * 1024 + n0 + cch*8;
#pragma unroll
    for (int i = 0; i < 8; i++) {
      const int row = r0 + i*16;
      bf16x8 v = *(const bf16x8*)&Ct[row*128 + ((cch ^ r0) << 3)];
      *(bf16x8*)(dst0 + (size_t)row * 1024) = v;
    }
  } else {
    const int bb = m0 / JD;
    const int jbase = m0 - bb * JD;
#pragma unroll
    for (int i = 0; i < 8; i++) {
      const int row = r0 + i*16;
      const int cc = n0 + row - 1024;
      bf16x8 v = *(const bf16x8*)&Ct[row*128 + ((cch ^ r0) << 3)];
      bf16* dst = outVT + (((size_t)(bb*HEADS + (cc >> 6)))*64 + (cc & 63)) * JD
                        + jbase + cch*8;
      *(bf16x8*)dst = v;
    }
  }
}

// ---------------- Attention --------------------------------------------------
// Grid 512 = (b,h) x 4 j-quarters. 512 thr (8 waves x 32 q-rows), Q-tile=256.
// K/V read once total. 48 KB LDS (Ps aliases Qs) -> 2 blocks/CU for drain
// overlap. f32 partial O + partial denominators; combined by attn_combine.
__global__ __launch_bounds__(512, 4) void attn_kernel(
    const bf16* __restrict__ Qrows,  // [2048][1024]
    const bf16* __restrict__ Krows,  // [B*JD][1024]
    const bf16* __restrict__ VT,     // [B][H][64][JD]
    const float* __restrict__ mmul,  // [B][JD]
    float* __restrict__ Opart,       // [4][2048][1024]
    float* __restrict__ dpart)       // [4][B][H][256]
{
  const int bh = blockIdx.x & 127, jq = blockIdx.x >> 7;
  const int b = bh >> 4, h = bh & 15;
  __shared__ bf16 smem[24 * 1024];       // 48 KB
  bf16* Qs  = smem;                       // 32 KB: 256x64; aliased by Ps later
  bf16* Ks  = smem + 16 * 1024;           // 8 KB: 64x64
  bf16* VTs = smem + 20 * 1024;           // 8 KB: 64x64
  const int tid = threadIdx.x, lane = tid & 63, w = tid >> 6;
  const int lc = lane & 15, lq = lane >> 4;
  bf16* Ps = smem + w * 2048;             // per-wave 32x64 (this wave's Qs rows)

  // ---- stage Q tile (256x64) and load this wave's fragments
  const bf16* Qg = Qrows + ((size_t)b * MQ) * 1024 + h * 64;
#pragma unroll
  for (int p = 0; p < 4; p++) {
    const int pp = p * 512 + tid, prow = pp >> 3, pc = pp & 7;
    gl_lds16(Qg + (size_t)prow * 1024 + (SWZ(prow, pc) << 3), &Qs[pp * 8]);
  }
  asm volatile("s_waitcnt vmcnt(0)" ::: "memory");
  __syncthreads();
  bf16x8 qf[2][2];
#pragma unroll
  for (int mi = 0; mi < 2; mi++)
#pragma unroll
    for (int kk = 0; kk < 2; kk++)
      qf[mi][kk] = *(const bf16x8*)&Qs[(w*32 + mi*16 + lc) * 64 + SWZ(lc, kk*4 + lq)*8];
  // (each wave's Ps region == its own Q rows; no cross-wave hazard)

  f32x4 oacc[2][4];
  float den[2][4];
#pragma unroll
  for (int mi = 0; mi < 2; mi++)
#pragma unroll
    for (int di = 0; di < 4; di++)
#pragma unroll
      for (int r = 0; r < 4; r++) oacc[mi][di][r] = 0.f;
#pragma unroll
  for (int mi = 0; mi < 2; mi++)
#pragma unroll
    for (int r = 0; r < 4; r++) den[mi][r] = 0.f;

  const bf16* Kg = Krows + (size_t)b * JD * 1024 + h * 64;
  const bf16* Vg = VT + (size_t)bh * 64 * JD;
  const int prow = tid >> 3, pc = tid & 7;
  const int psw = SWZ(prow, pc) << 3;
  const int j0base = jq * 1088;

  for (int it = 0; it < 17; it++) {
    const int j0 = j0base + it * 64;
    __syncthreads();
    gl_lds16(Kg + (size_t)(j0 + prow) * 1024 + psw, &Ks[tid * 8]);
    gl_lds16(Vg + (size_t)prow * JD + j0 + psw, &VTs[tid * 8]);
    const float mv = mmul[b * JD + j0 + lane];
    asm volatile("s_waitcnt vmcnt(0)" ::: "memory");
    __syncthreads();

    // S = Q K^T in two nj-halves (keeps sacc live range at 16 VGPR)
#pragma unroll
    for (int njh = 0; njh < 2; njh++) {
      f32x4 sacc[2][2];
#pragma unroll
      for (int mi = 0; mi < 2; mi++)
#pragma unroll
        for (int nj = 0; nj < 2; nj++)
#pragma unroll
          for (int r = 0; r < 4; r++) sacc[mi][nj][r] = 0.f;
#pragma unroll
      for (int kk = 0; kk < 2; kk++) {
        bf16x8 kf[2];
#pragma unroll
        for (int nj = 0; nj < 2; nj++)
          kf[nj] = *(const bf16x8*)&Ks[((njh*2 + nj)*16 + lc) * 64 + SWZ(lc, kk*4 + lq)*8];
#pragma unroll
        for (int mi = 0; mi < 2; mi++)
#pragma unroll
          for (int nj = 0; nj < 2; nj++)
            sacc[mi][nj] = __builtin_amdgcn_mfma_f32_16x16x32_bf16(qf[mi][kk], kf[nj], sacc[mi][nj], 0, 0, 0);
      }
#pragma unroll
      for (int nj = 0; nj < 2; nj++) {
        const float mm = __shfl(mv, (njh*2 + nj)*16 + lc);
        const int colb = (njh*2 + nj)*16 + lc;
#pragma unroll
        for (int mi = 0; mi < 2; mi++)
#pragma unroll
          for (int r = 0; r < 4; r++) {
            // scale*log2(e) = 0.125*1.4426950 = 0.18033688
            const float pv = exp2f(sacc[mi][nj][r] * 0.18033688f) * mm;
            den[mi][r] += pv;
            const int row = mi*16 + lq*4 + r;
            Ps[row*64 + (((colb >> 3) ^ (row & 7)) << 3) + (colb & 7)] = (bf16)pv;
          }
      }
    }

    // O += P V  (Ps is wave-private; in-wave LDS RAW ordering suffices)
#pragma unroll
    for (int kk = 0; kk < 2; kk++) {
      bf16x8 pf[2], vf[4];
#pragma unroll
      for (int mi = 0; mi < 2; mi++)
        pf[mi] = *(const bf16x8*)&Ps[(mi*16 + lc) * 64 + SWZ(lc, kk*4 + lq)*8];
#pragma unroll
      for (int di = 0; di < 4; di++)
        vf[di] = *(const bf16x8*)&VTs[(di*16 + lc) * 64 + SWZ(lc, kk*4 + lq)*8];
#pragma unroll
      for (int mi = 0; mi < 2; mi++)
#pragma unroll
        for (int di = 0; di < 4; di++)
          oacc[mi][di] = __builtin_amdgcn_mfma_f32_16x16x32_bf16(pf[mi], vf[di], oacc[mi][di], 0, 0, 0);
    }
  }

  // partial denominators: sum across the 16 lanes of each quad row-group
#pragma unroll
  for (int mi = 0; mi < 2; mi++)
#pragma unroll
    for (int r = 0; r < 4; r++) {
      float d = den[mi][r];
      d += __shfl_xor(d, 1); d += __shfl_xor(d, 2);
      d += __shfl_xor(d, 4); d += __shfl_xor(d, 8);
      den[mi][r] = d;
    }

#pragma unroll
  for (int mi = 0; mi < 2; mi++) {
#pragma unroll
    for (int di = 0; di < 4; di++) {
#pragma unroll
      for (int r = 0; r < 4; r++) {
        const int row = w*32 + mi*16 + lq*4 + r;
        Opart[((size_t)jq*2048 + b*256 + row) * 1024 + h*64 + di*16 + lc] = oacc[mi][di][r];
      }
    }
    if (lc == 0) {
#pragma unroll
      for (int r = 0; r < 4; r++) {
        const int row = w*32 + mi*16 + lq*4 + r;
        dpart[(((size_t)jq*8 + b)*16 + h)*256 + row] = den[mi][r];
      }
    }
  }
}

// ---------------- combine partials -> bf16 attention output ------------------
__global__ __launch_bounds__(256) void attn_combine(
    const float* __restrict__ Opart, const float* __restrict__ dpart,
    bf16* __restrict__ attout)
{
  const int r = blockIdx.x;           // 2048
  const int c = threadIdx.x * 4;      // col group
  const int b = r >> 8, i = r & 255, h = c >> 6;
  float4 o = make_float4(0.f, 0.f, 0.f, 0.f);
  float d = 0.f;
#pragma unroll
  for (int jq = 0; jq < 4; jq++) {
    const float4 t = *(const float4*)&Opart[((size_t)jq*2048 + r) * 1024 + c];
    o.x += t.x; o.y += t.y; o.z += t.z; o.w += t.w;
    d += dpart[(((size_t)jq*8 + b)*16 + h)*256 + i];
  }
  const float inv = 1.0f / d;
  union { bf16 hh[4]; short4 s4; } u;
  u.hh[0] = (bf16)(o.x * inv); u.hh[1] = (bf16)(o.y * inv);
  u.hh[2] = (bf16)(o.z * inv); u.hh[3] = (bf16)(o.w * inv);
  *(short4*)(attout + (size_t)r * 1024 + c) = u.s4;
}

// ---------------- launch -----------------------------------------------------
extern "C" void kernel_launch(void* const* d_in, const int* in_sizes, int n_in,
                              void* d_out, int out_size, void* d_ws, size_t ws_size,
                              hipStream_t stream)
{
  const float* x    = (const float*)d_in[0];
  const float* lat  = (const float*)d_in[1];
  const void*  mraw = d_in[2];
  const float* nm_g = (const float*)d_in[3];
  const float* nm_b = (const float*)d_in[4];
  const float* nl_g = (const float*)d_in[5];
  const float* nl_b = (const float*)d_in[6];
  const float* Wq   = (const float*)d_in[7];
  const float* Wkv  = (const float*)d_in[8];
  const float* Wo   = (const float*)d_in[9];
  float* out = (float*)d_out;

  char* p = (char*)d_ws;
  auto alloc = [&](size_t bytes) { char* r = p; p += (bytes + 255) & ~(size_t)255; return r; };

  bf16*  kv_in  = (bf16*)alloc((size_t)NB * JD * DIMV * 2);          // 71.3 MB
  bf16*  Krows  = (bf16*)alloc((size_t)NB * JD * 1024 * 2);          // 71.3 MB
  bf16*  VTbuf  = (bf16*)alloc((size_t)NB * HEADS * 64 * JD * 2);    // 71.3 MB
  bf16*  WqT    = (bf16*)alloc((size_t)1024 * 1024 * 2);
  bf16*  WkvT   = (bf16*)alloc((size_t)2048 * 1024 * 2);
  bf16*  WoT    = (bf16*)alloc((size_t)1024 * 1024 * 2);
  bf16*  ln_buf = (bf16*)alloc((size_t)NB * MQ * DIMV * 2);
  bf16*  Qrows  = (bf16*)alloc((size_t)NB * MQ * 1024 * 2);
  bf16*  attout = (bf16*)alloc((size_t)NB * MQ * DIMV * 2);
  float* mmulp  = (float*)alloc((size_t)NB * JD * 4);
  int*   flag   = (int*)alloc(256);
  // Attention partials alias kv_in (dead after the kv GEMM): 33.6 + 0.6 MB < 71.3 MB
  float* Opart = (float*)kv_in;
  float* dpart = Opart + (size_t)4 * 2048 * 1024;
  (void)ws_size; (void)in_sizes; (void)n_in; (void)out_size;

  ln_kernel<<<NB * MX / 4, 256, 0, stream>>>(x,   nm_g, nm_b, kv_in, nullptr, 0);
  ln_kernel<<<NB * MQ / 4, 256, 0, stream>>>(lat, nl_g, nl_b, kv_in, ln_buf, 1);
  transpose_w<<<256, 256, 0, stream>>>(Wq,  WqT,  1024, 1024);
  transpose_w<<<512, 256, 0, stream>>>(Wkv, WkvT, 1024, 2048);
  transpose_w<<<256, 256, 0, stream>>>(Wo,  WoT,  1024, 1024);
  mask_detect<<<1, 256, 0, stream>>>((const uint4*)mraw, 2048, flag);
  mask_build<<<136, 256, 0, stream>>>(mraw, flag, mmulp);

  // kv = kv_in @ Wkv, split into 4 dispatches (profiling visibility; same math)
  for (int q = 0; q < 4; q++)
    gemm128<<<dim3(16, 68), 256, 0, stream>>>(kv_in, WkvT, nullptr, Krows, VTbuf,
                                              2048, 1024, 8, 1, q * 68);
  // q = ln @ Wq -> natural rows [2048][1024]
  gemm128<<<dim3(8, 16), 256, 0, stream>>>(ln_buf, WqT, nullptr, Qrows, nullptr,
                                           1024, 1024, 8, 1, 0);
  attn_kernel<<<512, 512, 0, stream>>>(Qrows, Krows, VTbuf, mmulp, Opart, dpart);
  attn_combine<<<2048, 256, 0, stream>>>(Opart, dpart, attout);
  // out = attout @ Wo -> f32 d_out
  gemm128<<<dim3(8, 16), 256, 0, stream>>>(attout, WoT, out, nullptr, nullptr,
                                           1024, 1024, 8, 0, 0);
}